// Round 1
// baseline (1931.362 us; speedup 1.0000x reference)
//
#include <hip/hip_runtime.h>
#include <math.h>

#define B_ROWS 131072
#define D_DIM  1024
#define E_EXP  64
#define RPW    16     // rows per wave
#define DCHUNK 32     // d-values staged in VGPRs per iteration

// ---------- helpers ----------

__device__ __forceinline__ float softplus_f(float t) {
  // jax.nn.softplus = log1p(exp(t)); inputs here are ~N(0,0.64) so no overflow,
  // but guard anyway.
  return (t > 20.0f) ? t : log1pf(expf(t));
}

__device__ __forceinline__ float ndtr_f(float z) {
  return 0.5f * erfcf(-z * 0.70710678118654752f);
}

// wave-wide argmax over 64 lanes, ties -> smaller lane index (matches jax top_k)
__device__ __forceinline__ void argmax64(float& v, int& vi) {
  #pragma unroll
  for (int off = 32; off > 0; off >>= 1) {
    float ov = __shfl_xor(v, off, 64);
    int   oi = __shfl_xor(vi, off, 64);
    if (ov > v || (ov == v && oi < vi)) { v = ov; vi = oi; }
  }
}

__device__ __forceinline__ float sum64(float v) {
  #pragma unroll
  for (int off = 32; off > 0; off >>= 1) v += __shfl_xor(v, off, 64);
  return v;
}

// ---------- kernels ----------

__global__ void init_acc(float* load_o, float* imp_o, float* zsum) {
  int t = threadIdx.x;
  if (t < 64) { load_o[t] = 0.0f; imp_o[t] = 0.0f; }
  if (t == 64) zsum[0] = 0.0f;
}

__global__ __launch_bounds__(256) void router_main(
    const float* __restrict__ x,       // [B, D]
    const float* __restrict__ wgm,     // [D, E]
    const float* __restrict__ wnm,     // [D, E]
    const float* __restrict__ eps,     // [B, E]
    float* __restrict__ out_gates,     // [B, E]
    float* __restrict__ out_load,      // [E]
    float* __restrict__ out_logits,    // [B, E]
    float* __restrict__ out_imp,       // [E]
    float* __restrict__ zsum)          // [1] in workspace
{
  const int lane = threadIdx.x & 63;   // lane == expert index
  const int wid  = threadIdx.x >> 6;
  const int row0 = (blockIdx.x * 4 + wid) * RPW;

  float accg[RPW], accn[RPW];
  #pragma unroll
  for (int r = 0; r < RPW; ++r) { accg[r] = 0.0f; accn[r] = 0.0f; }

  // ---- fp32 GEMM: acc[r] = x[row] . w[:, lane] for both matrices ----
  for (int dt = 0; dt < D_DIM; dt += DCHUNK) {
    float wgv[DCHUNK], wnv[DCHUNK];
    #pragma unroll
    for (int j = 0; j < DCHUNK; ++j) {
      wgv[j] = wgm[(dt + j) * E_EXP + lane];   // coalesced, L1-resident chunk
      wnv[j] = wnm[(dt + j) * E_EXP + lane];
    }
    #pragma unroll
    for (int r = 0; r < RPW; ++r) {
      const float4* xp = reinterpret_cast<const float4*>(x + (size_t)(row0 + r) * D_DIM + dt);
      float xv[DCHUNK];
      #pragma unroll
      for (int q = 0; q < DCHUNK / 4; ++q) {
        float4 t = xp[q];                      // wave-uniform address -> broadcast
        xv[4*q+0] = t.x; xv[4*q+1] = t.y; xv[4*q+2] = t.z; xv[4*q+3] = t.w;
      }
      #pragma unroll
      for (int j = 0; j < DCHUNK; ++j) {
        accg[r] = fmaf(xv[j], wgv[j], accg[r]);
        accn[r] = fmaf(xv[j], wnv[j], accn[r]);
      }
    }
  }

  // ---- epilogue: per-row noisy top-k routing ----
  float load_acc = 0.0f, imp_acc = 0.0f, z_acc = 0.0f;

  #pragma unroll
  for (int r = 0; r < RPW; ++r) {
    const int row = row0 + r;
    const float clean  = accg[r];
    const float stddev = softplus_f(accn[r]) + 0.01f;
    const float ev     = eps[(size_t)row * E_EXP + lane];
    const float l      = fmaf(ev, stddev, clean);   // noisy logit for expert `lane`

    // top-3 of 64 lanes
    float v1 = l; int i1 = lane;
    argmax64(v1, i1);
    float v2 = (lane == i1) ? -INFINITY : l; int i2 = lane;
    argmax64(v2, i2);
    float v3 = (lane == i1 || lane == i2) ? -INFINITY : l; int i3 = lane;
    argmax64(v3, i3);
    (void)i3;

    // softmax over [v1, v2]
    const float e21 = expf(v2 - v1);
    const float g1  = 1.0f / (1.0f + e21);
    const float g2  = e21 * g1;
    const float gv  = (lane == i1) ? g1 : ((lane == i2) ? g2 : 0.0f);

    out_gates [(size_t)row * E_EXP + lane] = gv;
    out_logits[(size_t)row * E_EXP + lane] = l;

    // z-loss: logsumexp over experts (v1 is the max)
    const float ssum = sum64(expf(l - v1));
    z_acc += v1 + logf(ssum);

    // load: where(l > v3, ndtr((clean-v3)/sd), ndtr((clean-v2)/sd))
    const bool  isin = l > v3;
    const float thr  = isin ? v3 : v2;
    load_acc += ndtr_f((clean - thr) / stddev);
    imp_acc  += gv;
  }

  atomicAdd(&out_load[lane], load_acc);
  atomicAdd(&out_imp[lane],  imp_acc);
  if (lane == 0) atomicAdd(zsum, z_acc);
}

__global__ void finalize_k(const float* __restrict__ load_o,
                           const float* __restrict__ imp_o,
                           const float* __restrict__ zsum,
                           float* __restrict__ out_lb) {
  if (threadIdx.x == 0 && blockIdx.x == 0) {
    double sl = 0.0, sl2 = 0.0, si = 0.0, si2 = 0.0;
    for (int e = 0; e < E_EXP; ++e) {
      double a = (double)load_o[e]; sl += a; sl2 += a * a;
      double b = (double)imp_o[e];  si += b; si2 += b * b;
    }
    const double n  = (double)E_EXP;
    const double ml = sl / n, mi = si / n;
    const double varl = (sl2 - n * ml * ml) / (n - 1.0);
    const double vari = (si2 - n * mi * mi) / (n - 1.0);
    const double cvl = varl / (ml * ml + 1e-10);
    const double cvi = vari / (mi * mi + 1e-10);
    const double z  = (double)zsum[0] / (double)B_ROWS;
    out_lb[0] = (float)(cvi + cvl + z);
  }
}

// ---------- launch ----------

extern "C" void kernel_launch(void* const* d_in, const int* in_sizes, int n_in,
                              void* d_out, int out_size, void* d_ws, size_t ws_size,
                              hipStream_t stream) {
  const float* x   = (const float*)d_in[0];
  const float* wg  = (const float*)d_in[1];
  const float* wn  = (const float*)d_in[2];
  const float* eps = (const float*)d_in[3];

  float* out    = (float*)d_out;
  float* gates  = out;                         // [B*E]
  float* load_o = out + (size_t)B_ROWS * E_EXP;              // [E]
  float* logits = load_o + E_EXP;                            // [B*E]
  float* lb     = logits + (size_t)B_ROWS * E_EXP;           // [1]
  float* imp    = lb + 1;                                    // [E]
  float* zsum   = (float*)d_ws;                              // [1]

  init_acc<<<1, 128, 0, stream>>>(load_o, imp, zsum);
  router_main<<<B_ROWS / (4 * RPW), 256, 0, stream>>>(
      x, wg, wn, eps, gates, load_o, logits, imp, zsum);
  finalize_k<<<1, 64, 0, stream>>>(load_o, imp, zsum, lb);
}